// Round 6
// baseline (181.199 us; speedup 1.0000x reference)
//
#include <hip/hip_runtime.h>

namespace {
constexpr int N_ = 8, C_ = 32, H_ = 256, W_ = 512, DISP_ = 25;
constexpr int CH = H_ * W_;   // elements between channels / disparities
constexpr int SU = 4;         // channels staged per super-iteration
constexpr int NSU = C_ / SU;  // 8 super-iterations
}

// LDS-staged disparity-split kernel. 256 threads/block = one (n,h) row.
//   t = tid & 127 -> 4 output columns (w0 = 4t)
//   g = tid >> 7  -> disparity group (wave-uniform): g0 i in [0,13), g1 [13,25)
// Round-5 post-mortem: redundant y-window global reads (8x) made the kernel
// L1/L2-BW-bound. Fix: stage x,y rows in LDS (4 channels = 16 KB / superstep);
// global traffic per block-channel drops 32KB -> 4KB (compulsory minimum).
// g0 waves stage x, g1 waves stage y (which == G, compile-time); both template
// bodies execute identical barrier sequences (wave-uniform split).
// Next superstep's loads issue right after the stage barrier -> HBM latency
// hides under ~4 channels of compute; compute reads LDS only (no vmcnt drain).
template <int G>
__device__ __forceinline__ void body(const float* __restrict__ src,
                                     float* __restrict__ op, float* lds,
                                     const int* yoff, int w0, int t) {
  constexpr int NI = 13 - G;  // 13 or 12 disparities

  float acc[NI][4];
#pragma unroll
  for (int il = 0; il < NI; ++il)
#pragma unroll
    for (int cw = 0; cw < 4; ++cw) acc[il][cw] = 0.0f;

  // Prologue: issue superstep 0's loads (one float4 per channel per thread).
  float4 st[SU];
#pragma unroll
  for (int cc = 0; cc < SU; ++cc)
    st[cc] = *reinterpret_cast<const float4*>(src + (size_t)cc * CH + 4 * t);

#pragma unroll 1
  for (int su = 0; su < NSU; ++su) {
    __syncthreads();  // previous superstep's LDS reads complete
#pragma unroll
    for (int cc = 0; cc < SU; ++cc)
      *reinterpret_cast<float4*>(lds + (cc * 2 + G) * W_ + 4 * t) = st[cc];
    __syncthreads();  // staged data visible

    // Early-issue next superstep's global loads; consumed at next ds_write.
    if (su + 1 < NSU) {
      const float* s2 = src + (size_t)(su + 1) * SU * CH;
#pragma unroll
      for (int cc = 0; cc < SU; ++cc)
        st[cc] = *reinterpret_cast<const float4*>(s2 + (size_t)cc * CH + 4 * t);
    }

#pragma unroll
    for (int cc = 0; cc < SU; ++cc) {
      const float* lx = lds + (cc * 2 + 0) * W_;
      const float* ly = lds + (cc * 2 + 1) * W_;
      const float4 xv = *reinterpret_cast<const float4*>(lx + w0);
      float4 yv[4];
#pragma unroll
      for (int k = 0; k < 4; ++k)
        yv[k] = *reinterpret_cast<const float4*>(ly + yoff[k]);

      const float xs[4] = {xv.x, xv.y, xv.z, xv.w};
      const float ywin[16] = {yv[0].x, yv[0].y, yv[0].z, yv[0].w,
                              yv[1].x, yv[1].y, yv[1].z, yv[1].w,
                              yv[2].x, yv[2].y, yv[2].z, yv[2].w,
                              yv[3].x, yv[3].y, yv[3].z, yv[3].w};
#pragma unroll
      for (int il = 0; il < NI; ++il) {
#pragma unroll
        for (int cw = 0; cw < 4; ++cw) {
          acc[il][cw] += fabsf(xs[cw] - ywin[cw + 12 - G - il]);
        }
      }
    }
  }

  // Epilogue: zero out-of-overlap (w,i) pairs, coalesced float4 stores.
#pragma unroll
  for (int il = 0; il < NI; ++il) {
    const int i = 13 * G + il;
    const int j0 = w0 - i + 12;  // y column used by cw=0
    float4 v;
    v.x = ((unsigned)(j0 + 0) < (unsigned)W_) ? acc[il][0] : 0.0f;
    v.y = ((unsigned)(j0 + 1) < (unsigned)W_) ? acc[il][1] : 0.0f;
    v.z = ((unsigned)(j0 + 2) < (unsigned)W_) ? acc[il][2] : 0.0f;
    v.w = ((unsigned)(j0 + 3) < (unsigned)W_) ? acc[il][3] : 0.0f;
    *reinterpret_cast<float4*>(op + (size_t)i * CH) = v;
  }
}

__global__ __launch_bounds__(256, 4) void rescost_kernel(
    const float* __restrict__ x, const float* __restrict__ y,
    float* __restrict__ out) {
  __shared__ __align__(16) float lds[SU * 2 * W_];  // 16 KB

  const int tid = threadIdx.x;
  const int t = tid & 127;   // column group
  const int g = tid >> 7;    // disparity group == staging role (wave-uniform)
  const int r = blockIdx.x;  // row in [0, N*H)
  const int n = r >> 8;      // H = 256
  const int h = r & (H_ - 1);
  const int w0 = t << 2;

  // 4 clamped 16B-aligned y-window offsets; base = w0 - 12*g. Each float4
  // window is fully in [0,W) or fully OOB (base mult of 4); clamped windows
  // only feed epilogue-zeroed outputs.
  int yoff[4];
  const int ybase = w0 - 12 * g;
#pragma unroll
  for (int k = 0; k < 4; ++k) {
    int idx = ybase + 4 * k;
    idx = idx < 0 ? 0 : idx;
    idx = idx > (W_ - 4) ? (W_ - 4) : idx;
    yoff[k] = idx;
  }

  const size_t row_base = ((size_t)n * C_ * H_ + (size_t)h) * W_;
  float* op = out + ((size_t)n * DISP_ * H_ + (size_t)h) * W_ + w0;

  if (g == 0)
    body<0>(x + row_base, op, lds, yoff, w0, t);
  else
    body<1>(y + row_base, op, lds, yoff, w0, t);
}

extern "C" void kernel_launch(void* const* d_in, const int* in_sizes, int n_in,
                              void* d_out, int out_size, void* d_ws, size_t ws_size,
                              hipStream_t stream) {
  const float* x = (const float*)d_in[0];
  const float* y = (const float*)d_in[1];
  float* out = (float*)d_out;
  dim3 grid(N_ * H_);  // one (n,h) row per block
  dim3 block(256);
  hipLaunchKernelGGL(rescost_kernel, grid, block, 0, stream, x, y, out);
}